// Round 1
// 1534.874 us; speedup vs baseline: 1.2428x; 1.2428x over previous
//
#include <hip/hip_runtime.h>
#include <stdint.h>

// out[b,d,n] = sum_m adj[b,n,m] * x[b,d,m]
// GEMM: C[m,n] = sum_k A[m,k] * B[n,k], A = x (3072x8192), B = adj (8192x8192), per batch.
#define GM 3072
#define GN 8192
#define GK 8192
#define GB 2

typedef __bf16 bf16x8 __attribute__((ext_vector_type(8)));
typedef float f32x4 __attribute__((ext_vector_type(4)));
typedef unsigned short u16x8 __attribute__((ext_vector_type(8)));

__device__ __forceinline__ unsigned short f2bf(float f) {
  union { float f; unsigned u; } v; v.f = f;
  return (unsigned short)((v.u + 0x7FFFu + ((v.u >> 16) & 1u)) >> 16);  // RTNE
}

__device__ __forceinline__ void gl2lds16(const void* g, void* l) {
  // async 16B/lane global->LDS; LDS dest = wave-uniform base + lane*16
  __builtin_amdgcn_global_load_lds(
      (const __attribute__((address_space(1))) unsigned int*)g,
      (__attribute__((address_space(3))) unsigned int*)l, 16, 0, 0);
}

__global__ void cvt_f32_bf16(const float4* __restrict__ in,
                             ushort4* __restrict__ out, int n4) {
  int i = blockIdx.x * blockDim.x + threadIdx.x;
  int stride = gridDim.x * blockDim.x;
  for (; i < n4; i += stride) {
    float4 f = in[i];
    ushort4 o;
    o.x = f2bf(f.x); o.y = f2bf(f.y); o.z = f2bf(f.z); o.w = f2bf(f.w);
    out[i] = o;
  }
}

// ---------------------------------------------------------------------------
// Fallback (ws too small): previous verified 128x128 kernel, fp32 reg staging.
// ---------------------------------------------------------------------------
#define BM 128
#define BN 128
#define BK 64

template <bool ASYNC>
__global__ __launch_bounds__(256) void gcn_gemm(const void* __restrict__ Av,
                                                const void* __restrict__ Bv,
                                                float* __restrict__ C) {
  __shared__ __attribute__((aligned(16))) uint16_t sA[BM * BK];
  __shared__ __attribute__((aligned(16))) uint16_t sB[BN * BK];

  const int tid = threadIdx.x;
  const int lane = tid & 63;
  const int w = tid >> 6;
  const int wm = w >> 1;
  const int wn = w & 1;
  const int t16 = lane & 15;
  const int q = lane >> 4;

  const int b = blockIdx.z;
  const int m0 = blockIdx.y * BM;
  const int n0 = blockIdx.x * BN;

  f32x4 acc[4][4] = {};
  const int swz = t16 & 7;

  for (int k0 = 0; k0 < GK; k0 += BK) {
    {
      const float* Af = (const float*)Av + (size_t)b * GM * GK + (size_t)m0 * GK + k0;
      const float* Bf = (const float*)Bv + (size_t)b * GN * GK + (size_t)n0 * GK + k0;
#pragma unroll
      for (int i = 0; i < 4; i++) {
        const int t = i * 256 + tid;
        const int row = t >> 3;
        const int segg = (t & 7) ^ (row & 7);
        {
          const float* p = Af + (size_t)row * GK + segg * 8;
          float4 f0 = *(const float4*)p;
          float4 f1 = *(const float4*)(p + 4);
          u16x8 vv = {f2bf(f0.x), f2bf(f0.y), f2bf(f0.z), f2bf(f0.w),
                      f2bf(f1.x), f2bf(f1.y), f2bf(f1.z), f2bf(f1.w)};
          *(u16x8*)((char*)sA + (size_t)t * 16) = vv;
        }
        {
          const float* p = Bf + (size_t)row * GK + segg * 8;
          float4 f0 = *(const float4*)p;
          float4 f1 = *(const float4*)(p + 4);
          u16x8 vv = {f2bf(f0.x), f2bf(f0.y), f2bf(f0.z), f2bf(f0.w),
                      f2bf(f1.x), f2bf(f1.y), f2bf(f1.z), f2bf(f1.w)};
          *(u16x8*)((char*)sB + (size_t)t * 16) = vv;
        }
      }
    }
    __syncthreads();

#pragma unroll
    for (int s = 0; s < BK / 32; s++) {
      bf16x8 af[4], bfr[4];
#pragma unroll
      for (int i = 0; i < 4; i++) {
        const int r = wm * 64 + i * 16 + t16;
        af[i] = *(const bf16x8*)((const char*)sA + r * (BK * 2) +
                                 (((s * 4 + q) ^ swz) * 16));
      }
#pragma unroll
      for (int j = 0; j < 4; j++) {
        const int r = wn * 64 + j * 16 + t16;
        bfr[j] = *(const bf16x8*)((const char*)sB + r * (BK * 2) +
                                  (((s * 4 + q) ^ swz) * 16));
      }
#pragma unroll
      for (int i = 0; i < 4; i++)
#pragma unroll
        for (int j = 0; j < 4; j++)
          acc[i][j] = __builtin_amdgcn_mfma_f32_16x16x32_bf16(af[i], bfr[j],
                                                              acc[i][j], 0, 0, 0);
    }
    __syncthreads();
  }

  float* Cp = C + (size_t)b * GM * GN;
#pragma unroll
  for (int i = 0; i < 4; i++) {
    const int rowb = m0 + wm * 64 + i * 16 + q * 4;
#pragma unroll
    for (int j = 0; j < 4; j++) {
      const int col = n0 + wn * 64 + j * 16 + t16;
#pragma unroll
      for (int r = 0; r < 4; r++)
        Cp[(size_t)(rowb + r) * GN + col] = acc[i][j][r];
    }
  }
}

// ---------------------------------------------------------------------------
// Main kernel: 256x256 tile, BK=64, 8 waves (2x4), 8-phase counted-vmcnt
// pipeline (T3+T4) + setprio (T5). LDS 128 KiB double-buffered, k-half-major:
//   smem[buf][mat(A=0,B=1)][khalf][256 rows x 32 bf16]
// Each half-tile (16 KB) is a contiguous gl2lds destination (linear, rule #21);
// the bank swizzle is applied on the SOURCE addresses: LDS slot (row, qs)
// holds k-chunk (qs ^ ((row>>1)&3)). ds_read_b128 fragments then land 2
// lanes/16B-granule -> conflict-free (same involution family that measured
// SQ_LDS_BANK_CONFLICT = 0 on the previous kernel).
// ---------------------------------------------------------------------------
#define CBM 256
#define CBN 256
#define CBK 64
#define NTILES (GK / CBK)   // 128 K-tiles
#define NITER (NTILES / 2)  // 64 iterations, 2 tiles each

// stage one half-tile: 1024 slots of 16B, thread handles slots tid and tid+512
#define STAGE(Base, kt, kh, dstp)                                              \
  do {                                                                         \
    const uint16_t* src_ = (Base) + (size_t)(kt) * CBK + (kh) * 32;            \
    _Pragma("unroll") for (int si_ = 0; si_ < 2; si_++) {                      \
      const int t_ = si_ * 512 + tid;                                          \
      const int row_ = t_ >> 2;                                                \
      const int qs_ = (t_ & 3) ^ ((row_ >> 1) & 3);                            \
      gl2lds16(src_ + (size_t)row_ * GK + qs_ * 8,                             \
               (char*)(dstp) + ((si_ * 512 + (tid & ~63)) * 16));              \
    }                                                                          \
  } while (0)

#define VM6 asm volatile("s_waitcnt vmcnt(6)" ::: "memory")
#define VM0 asm volatile("s_waitcnt vmcnt(0)" ::: "memory")
#define NOVM ((void)0)
#define NOST ((void)0)

// One phase: {c = buffer, s = k-step (== k-half), h = m-half of wave's frags}.
// reads (8 on h==0: 4 B + 4 A; 4 on h==1: 4 A) || stage || [vmcnt] ->
// barrier -> lgkmcnt(0) -> setprio(1) 16 MFMA setprio(0) -> barrier.
// sched_barrier(0) pins the raw-barrier boundaries (no cross-phase motion).
#define PHASE(c, s, h, STAGES, VM)                                             \
  do {                                                                         \
    const char* Ar_ = (const char*)&smem[c][0][s][0];                          \
    const char* Br_ = (const char*)&smem[c][1][s][0];                          \
    if ((h) == 0) {                                                            \
      _Pragma("unroll") for (int j_ = 0; j_ < 4; j_++)                         \
          bfr[j_] = *(const bf16x8*)(Br_ + (wn * 64 + j_ * 16 + t16) * 64 + qp); \
    }                                                                          \
    _Pragma("unroll") for (int fi_ = 0; fi_ < 4; fi_++)                        \
        af[fi_] = *(const bf16x8*)(Ar_ + (wm * 128 + (h) * 64 + fi_ * 16 + t16) * 64 + qp); \
    STAGES;                                                                    \
    VM;                                                                        \
    __builtin_amdgcn_sched_barrier(0);                                         \
    __builtin_amdgcn_s_barrier();                                              \
    asm volatile("s_waitcnt lgkmcnt(0)" ::: "memory");                         \
    __builtin_amdgcn_sched_barrier(0);                                         \
    __builtin_amdgcn_s_setprio(1);                                             \
    _Pragma("unroll") for (int fi_ = 0; fi_ < 4; fi_++)                        \
        _Pragma("unroll") for (int j_ = 0; j_ < 4; j_++)                       \
            acc[(h) * 4 + fi_][j_] = __builtin_amdgcn_mfma_f32_16x16x32_bf16(  \
                af[fi_], bfr[j_], acc[(h) * 4 + fi_][j_], 0, 0, 0);            \
    __builtin_amdgcn_s_setprio(0);                                             \
    __builtin_amdgcn_sched_barrier(0);                                         \
    __builtin_amdgcn_s_barrier();                                              \
  } while (0)

__global__ __launch_bounds__(512, 2) void gcn_gemm256(
    const uint16_t* __restrict__ A, const uint16_t* __restrict__ B,
    float* __restrict__ C) {
  __shared__ __attribute__((aligned(16))) uint16_t smem[2][2][2][256 * 32];

  const int tid = threadIdx.x;
  const int lane = tid & 63;
  const int w = tid >> 6;       // 8 waves: 2 (m) x 4 (n)
  const int wm = w >> 2;
  const int wn = w & 3;
  const int t16 = lane & 15;
  const int q = lane >> 4;
  const int qp = (q ^ ((t16 >> 1) & 3)) << 4;  // swizzled 16B slot byte-offset

  const int b = blockIdx.z;
  const int m0 = blockIdx.y * CBM;
  const int n0 = blockIdx.x * CBN;

  const uint16_t* Ab = A + (size_t)b * GM * GK + (size_t)m0 * GK;
  const uint16_t* Bb = B + (size_t)b * GN * GK + (size_t)n0 * GK;

  f32x4 acc[8][4] = {};
  bf16x8 af[4], bfr[4];

  // Prologue: tile0 fully (4 halves) + tile1 {B-k0, A-k0, B-k1}.
  // vmcnt(6) leaves exactly tile1's 3 halves in flight -> tile0 published.
  STAGE(Ab, 0, 0, &smem[0][0][0][0]);
  STAGE(Ab, 0, 1, &smem[0][0][1][0]);
  STAGE(Bb, 0, 0, &smem[0][1][0][0]);
  STAGE(Bb, 0, 1, &smem[0][1][1][0]);
  STAGE(Bb, 1, 0, &smem[1][1][0][0]);
  STAGE(Ab, 1, 0, &smem[1][0][0][0]);
  STAGE(Bb, 1, 1, &smem[1][1][1][0]);
  VM6;
  __builtin_amdgcn_sched_barrier(0);
  __builtin_amdgcn_s_barrier();

  // Steady state: each stage slot is exactly one barrier after the staged
  // region's last read; vmcnt(6) at ph4 publishes tile 2i+1, at ph8 tile 2i+2.
  for (int it = 0; it < NITER - 1; ++it) {
    const int tO = 2 * it + 1;
    const int tE2 = 2 * it + 2;
    const int tO2 = 2 * it + 3;
    PHASE(0, 0, 0, STAGE(Ab, tO, 1, &smem[1][0][1][0]), NOVM);
    PHASE(0, 0, 1, STAGE(Bb, tE2, 0, &smem[0][1][0][0]), NOVM);
    PHASE(0, 1, 0, STAGE(Ab, tE2, 0, &smem[0][0][0][0]), NOVM);
    PHASE(0, 1, 1, STAGE(Bb, tE2, 1, &smem[0][1][1][0]), VM6);
    PHASE(1, 0, 0, STAGE(Ab, tE2, 1, &smem[0][0][1][0]), NOVM);
    PHASE(1, 0, 1, STAGE(Bb, tO2, 0, &smem[1][1][0][0]), NOVM);
    PHASE(1, 1, 0, STAGE(Ab, tO2, 0, &smem[1][0][0][0]), NOVM);
    PHASE(1, 1, 1, STAGE(Bb, tO2, 1, &smem[1][1][1][0]), VM6);
  }

  // Peeled last iteration (tiles 126,127): only ph1's stage remains;
  // ph4 must fully drain (vmcnt(0)) to publish tile 127.
  PHASE(0, 0, 0, STAGE(Ab, NTILES - 1, 1, &smem[1][0][1][0]), NOVM);
  PHASE(0, 0, 1, NOST, NOVM);
  PHASE(0, 1, 0, NOST, NOVM);
  PHASE(0, 1, 1, NOST, VM0);
  PHASE(1, 0, 0, NOST, NOVM);
  PHASE(1, 0, 1, NOST, NOVM);
  PHASE(1, 1, 0, NOST, NOVM);
  PHASE(1, 1, 1, NOST, NOVM);

  // C/D layout (m89-verified): col = lane&15 (n), row = (lane>>4)*4 + reg (m)
  float* Cp = C + (size_t)b * GM * GN;
#pragma unroll
  for (int i = 0; i < 8; i++) {
    const int rowb = m0 + wm * 128 + i * 16 + q * 4;
#pragma unroll
    for (int j = 0; j < 4; j++) {
      const int col = n0 + wn * 64 + j * 16 + t16;
#pragma unroll
      for (int r = 0; r < 4; r++)
        Cp[(size_t)(rowb + r) * GN + col] = acc[i][j][r];
    }
  }
}

extern "C" void kernel_launch(void* const* d_in, const int* in_sizes, int n_in,
                              void* d_out, int out_size, void* d_ws, size_t ws_size,
                              hipStream_t stream) {
  const float* x = (const float*)d_in[0];    // (B, D, N) = (2, 3072, 8192)
  const float* adj = (const float*)d_in[1];  // (B, N, N) = (2, 8192, 8192)
  float* out = (float*)d_out;                // (B, D, N)

  const size_t xe = (size_t)GB * GM * GK;            // 50,331,648
  const size_t ae = (size_t)GB * GN * GK;            // 134,217,728
  const size_t need = (xe + ae) * sizeof(uint16_t);  // ~352 MiB

  if (ws_size >= need) {
    uint16_t* xb = (uint16_t*)d_ws;
    uint16_t* ab = xb + xe;
    cvt_f32_bf16<<<4096, 256, 0, stream>>>((const float4*)x, (ushort4*)xb, (int)(xe / 4));
    cvt_f32_bf16<<<4096, 256, 0, stream>>>((const float4*)adj, (ushort4*)ab, (int)(ae / 4));
    dim3 grid(GN / CBN, GM / CBM, GB);  // (32, 12, 2)
    gcn_gemm256<<<grid, 512, 0, stream>>>(xb, ab, out);
  } else {
    dim3 grid(GN / BN, GM / BM, GB);  // (64, 24, 2)
    gcn_gemm<false><<<grid, 256, 0, stream>>>(x, adj, out);
  }
}